// Round 4
// baseline (202.961 us; speedup 1.0000x reference)
//
#include <hip/hip_runtime.h>

// Node record layout (stride 16 floats = 64B):
//   [0..8]   Frame[k][j] (row-major)
//   [9..11]  pF[j] = sum_k pos[k]*Frame[k][j]
//   [12..14] pos[0..2]
//   [15]     sA = sum_{h,j} silu(A[h][j]) * Wa[waOff + h*3 + j]
#define REC_STRIDE 16

#define KPB 128        // keys per bin
#define KPB_SHIFT 7
#define EPB 16384      // edges per hist/scatter block
#define MAXBINS 1024

__device__ __forceinline__ float silu_f(float x)
{
    return x * __builtin_amdgcn_rcpf(1.f + __expf(-x));
}

__global__ void pre_node(const float* __restrict__ vec, const float* __restrict__ frame,
                         const float* __restrict__ pos, const float* __restrict__ W,
                         const float* __restrict__ Wa, int waOff,
                         float* __restrict__ out, int n)
{
    int i = blockIdx.x * blockDim.x + threadIdx.x;
    if (i >= n) return;

    float w[16][3];
#pragma unroll
    for (int d = 0; d < 16; ++d) {
        w[d][0] = W[d * 3 + 0];
        w[d][1] = W[d * 3 + 1];
        w[d][2] = W[d * 3 + 2];
    }
    float vt[3][3] = {{0.f}};  // [k][h]
    const float* vp = vec + (size_t)i * 48;
#pragma unroll
    for (int d = 0; d < 16; ++d) {
        float r0 = vp[d * 3 + 0], r1 = vp[d * 3 + 1], r2 = vp[d * 3 + 2];
#pragma unroll
        for (int h = 0; h < 3; ++h) {
            vt[0][h] += r0 * w[d][h];
            vt[1][h] += r1 * w[d][h];
            vt[2][h] += r2 * w[d][h];
        }
    }
    float F[9];
#pragma unroll
    for (int j = 0; j < 9; ++j) F[j] = frame[(size_t)i * 9 + j];
    float p0 = pos[(size_t)i * 3 + 0];
    float p1 = pos[(size_t)i * 3 + 1];
    float p2 = pos[(size_t)i * 3 + 2];

    float sA = 0.f;
#pragma unroll
    for (int h = 0; h < 3; ++h)
#pragma unroll
        for (int j = 0; j < 3; ++j) {
            float a = vt[0][h] * F[0 + j] + vt[1][h] * F[3 + j] + vt[2][h] * F[6 + j];
            sA += silu_f(a) * Wa[waOff + h * 3 + j];
        }

    float o[16];
#pragma unroll
    for (int j = 0; j < 9; ++j) o[j] = F[j];
#pragma unroll
    for (int j = 0; j < 3; ++j) o[9 + j] = p0 * F[j] + p1 * F[3 + j] + p2 * F[6 + j];
    o[12] = p0; o[13] = p1; o[14] = p2;
    o[15] = sA;

    float4* op = (float4*)(out + (size_t)i * REC_STRIDE);
#pragma unroll
    for (int q = 0; q < 4; ++q) op[q] = ((const float4*)o)[q];
}

// atomic-free edge score: out[e] = exp(raw)
__global__ void edge_score_ne(const int* __restrict__ inc,
                              const float* __restrict__ fromRec, const float* __restrict__ toRec,
                              const float* __restrict__ Wa,
                              float* __restrict__ ex_out, int E)
{
    int e = blockIdx.x * blockDim.x + threadIdx.x;
    if (e >= E) return;
    int fi = __builtin_nontemporal_load(inc + e);
    int ti = __builtin_nontemporal_load(inc + E + e);

    float fr[16], tr[16];
    const float4* fp4 = (const float4*)(fromRec + (size_t)fi * REC_STRIDE);
    const float4* tp4 = (const float4*)(toRec + (size_t)ti * REC_STRIDE);
#pragma unroll
    for (int q = 0; q < 4; ++q) ((float4*)fr)[q] = fp4[q];
#pragma unroll
    for (int q = 0; q < 4; ++q) ((float4*)tr)[q] = tp4[q];

    float wa9 = Wa[9], wa10 = Wa[10], wa11 = Wa[11];
    float wa21 = Wa[21], wa22 = Wa[22], wa23 = Wa[23];

    float raw = fr[15] + tr[15];
#pragma unroll
    for (int j = 0; j < 3; ++j) {
        float fd = tr[12] * fr[j] + tr[13] * fr[3 + j] + tr[14] * fr[6 + j] - fr[9 + j];
        float td = fr[12] * tr[j] + fr[13] * tr[3 + j] + fr[14] * tr[6 + j] - tr[9 + j];
        float waf = (j == 0) ? wa9 : (j == 1) ? wa10 : wa11;
        float wat = (j == 0) ? wa21 : (j == 1) ? wa22 : wa23;
        raw += silu_f(fd) * waf + silu_f(td) * wat;
    }

    float ex = __expf(raw);  // shift-invariant softmax, |raw| << 80
    __builtin_nontemporal_store(ex, ex_out + e);
}

__global__ void hist_kernel(const int* __restrict__ inc, int E, int nbins,
                            unsigned* __restrict__ hist)
{
    __shared__ unsigned cnt[MAXBINS];
    for (int t = threadIdx.x; t < nbins; t += blockDim.x) cnt[t] = 0;
    __syncthreads();
    int base = blockIdx.x * EPB;
    int end = min(base + EPB, E);
    for (int e = base + threadIdx.x; e < end; e += blockDim.x) {
        int fi = __builtin_nontemporal_load(inc + e);
        atomicAdd(&cnt[fi >> KPB_SHIFT], 1u);
    }
    __syncthreads();
    for (int t = threadIdx.x; t < nbins; t += blockDim.x)
        hist[(size_t)blockIdx.x * nbins + t] = cnt[t];
}

// single block; converts hist[blk][bin] in-place to exclusive offsets, writes binStart
__global__ void scan_kernel(unsigned* __restrict__ hist, unsigned* __restrict__ binStart,
                            int nblk, int nbins)
{
    __shared__ unsigned tot[MAXBINS];
    __shared__ unsigned bs[MAXBINS + 1];
    int t = threadIdx.x;
    if (t < nbins) {
        unsigned s = 0;
        for (int b = 0; b < nblk; ++b) s += hist[(size_t)b * nbins + t];
        tot[t] = s;
    }
    __syncthreads();
    if (t == 0) {
        unsigned run = 0;
        for (int i = 0; i < nbins; ++i) { bs[i] = run; run += tot[i]; }
        bs[nbins] = run;
    }
    __syncthreads();
    if (t < nbins) {
        unsigned run = bs[t];
        for (int b = 0; b < nblk; ++b) {
            unsigned h = hist[(size_t)b * nbins + t];
            hist[(size_t)b * nbins + t] = run;
            run += h;
        }
    }
    if (t <= nbins) binStart[t] = bs[t];
}

__global__ void scatter_kernel(const int* __restrict__ inc, const float* __restrict__ ex,
                               const unsigned* __restrict__ offs,
                               unsigned long long* __restrict__ pairs,
                               int E, int nbins)
{
    __shared__ unsigned cur[MAXBINS];
    for (int t = threadIdx.x; t < nbins; t += blockDim.x)
        cur[t] = offs[(size_t)blockIdx.x * nbins + t];
    __syncthreads();
    int base = blockIdx.x * EPB;
    int end = min(base + EPB, E);
    for (int e = base + threadIdx.x; e < end; e += blockDim.x) {
        int fi = __builtin_nontemporal_load(inc + e);
        float v = ex[e];
        unsigned slot = atomicAdd(&cur[fi >> KPB_SHIFT], 1u);
        unsigned long long p = ((unsigned long long)(unsigned)fi << 32)
                             | (unsigned long long)__float_as_uint(v);
        __builtin_nontemporal_store(p, pairs + slot);
    }
}

__global__ void binsum_kernel(const unsigned long long* __restrict__ pairs,
                              const unsigned* __restrict__ binStart,
                              float* __restrict__ segsum, int NF)
{
    __shared__ float acc[KPB];
    int b = blockIdx.x;
    if (threadIdx.x < KPB) acc[threadIdx.x] = 0.f;
    __syncthreads();
    unsigned s0 = binStart[b], s1 = binStart[b + 1];
    int keyBase = b << KPB_SHIFT;
    for (unsigned s = s0 + threadIdx.x; s < s1; s += blockDim.x) {
        unsigned long long p = pairs[s];
        int key = (int)(unsigned)(p >> 32);
        float v = __uint_as_float((unsigned)(p & 0xFFFFFFFFu));
        atomicAdd(&acc[key - keyBase], v);
    }
    __syncthreads();
    int k = keyBase + threadIdx.x;
    if (threadIdx.x < KPB && k < NF) segsum[k] = acc[threadIdx.x];
}

__global__ void edge_norm(const int* __restrict__ inc, const float* __restrict__ segsum,
                          float* __restrict__ out, int E)
{
    int e = blockIdx.x * blockDim.x + threadIdx.x;
    if (e >= E) return;
    int fi = __builtin_nontemporal_load(inc + e);
    float ex = out[e];
    __builtin_nontemporal_store(ex * __builtin_amdgcn_rcpf(segsum[fi]), out + e);
}

// -------- fallback: atomic edge_score (validated round 2) ----------
__global__ void edge_score_at(const int* __restrict__ inc,
                              const float* __restrict__ fromRec, const float* __restrict__ toRec,
                              const float* __restrict__ Wa,
                              float* __restrict__ ex_out, float* __restrict__ segsum, int E)
{
    int e = blockIdx.x * blockDim.x + threadIdx.x;
    if (e >= E) return;
    int fi = inc[e];
    int ti = inc[E + e];
    float fr[16], tr[16];
    const float4* fp4 = (const float4*)(fromRec + (size_t)fi * REC_STRIDE);
    const float4* tp4 = (const float4*)(toRec + (size_t)ti * REC_STRIDE);
#pragma unroll
    for (int q = 0; q < 4; ++q) ((float4*)fr)[q] = fp4[q];
#pragma unroll
    for (int q = 0; q < 4; ++q) ((float4*)tr)[q] = tp4[q];
    float raw = fr[15] + tr[15];
#pragma unroll
    for (int j = 0; j < 3; ++j) {
        float fd = tr[12] * fr[j] + tr[13] * fr[3 + j] + tr[14] * fr[6 + j] - fr[9 + j];
        float td = fr[12] * tr[j] + fr[13] * tr[3 + j] + fr[14] * tr[6 + j] - tr[9 + j];
        raw += silu_f(fd) * Wa[9 + j] + silu_f(td) * Wa[21 + j];
    }
    float ex = __expf(raw);
    ex_out[e] = ex;
    atomicAdd(&segsum[fi], ex);
}

extern "C" void kernel_launch(void* const* d_in, const int* in_sizes, int n_in,
                              void* d_out, int out_size, void* d_ws, size_t ws_size,
                              hipStream_t stream)
{
    const float* from_vec   = (const float*)d_in[0];
    const float* to_vec     = (const float*)d_in[1];
    const float* from_frame = (const float*)d_in[2];
    const float* to_frame   = (const float*)d_in[3];
    const float* from_pos   = (const float*)d_in[4];
    const float* to_pos     = (const float*)d_in[5];
    const float* W_from     = (const float*)d_in[6];
    const float* W_to       = (const float*)d_in[7];
    const float* W_attn     = (const float*)d_in[8];
    const int*   inc        = (const int*)d_in[9];

    const int NF = in_sizes[0] / 48;   // 50000
    const int NT = in_sizes[1] / 48;   // 100000
    const int E  = in_sizes[9] / 2;    // 1600000

    float* out = (float*)d_out;
    unsigned char* ws = (unsigned char*)d_ws;

    const int nbins = (NF + KPB - 1) >> KPB_SHIFT;
    const int nblk  = (E + EPB - 1) / EPB;

    // region A: pairs (E*8B) overlaid on node records ((NF+NT)*64B) — sequential lifetimes
    size_t regionA = (size_t)E * 8;
    size_t recsz   = ((size_t)NF + NT) * REC_STRIDE * 4;
    if (recsz > regionA) regionA = recsz;
    size_t offSeg  = (regionA + 255) & ~(size_t)255;
    size_t offHist = offSeg + (size_t)NF * 4;
    size_t offBS   = offHist + (size_t)nblk * nbins * 4;
    size_t needFull = offBS + (size_t)(nbins + 1) * 4;
    size_t needAtomic = recsz + (size_t)NF * 4;

    const int B = 256;
    if (ws_size >= needFull && nbins <= MAXBINS && nbins + 1 <= 1024) {
        float*    fromRec  = (float*)(ws);
        float*    toRec    = (float*)(ws + (size_t)NF * REC_STRIDE * 4);
        unsigned long long* pairs = (unsigned long long*)(ws);
        float*    segsum   = (float*)(ws + offSeg);
        unsigned* hist     = (unsigned*)(ws + offHist);
        unsigned* binStart = (unsigned*)(ws + offBS);

        pre_node<<<(NF + B - 1) / B, B, 0, stream>>>(from_vec, from_frame, from_pos, W_from, W_attn, 0,  fromRec, NF);
        pre_node<<<(NT + B - 1) / B, B, 0, stream>>>(to_vec, to_frame, to_pos, W_to, W_attn, 12, toRec, NT);
        edge_score_ne<<<(E + B - 1) / B, B, 0, stream>>>(inc, fromRec, toRec, W_attn, out, E);
        hist_kernel<<<nblk, B, 0, stream>>>(inc, E, nbins, hist);
        scan_kernel<<<1, 1024, 0, stream>>>(hist, binStart, nblk, nbins);
        scatter_kernel<<<nblk, B, 0, stream>>>(inc, out, hist, pairs, E, nbins);
        binsum_kernel<<<nbins, B, 0, stream>>>(pairs, binStart, segsum, NF);
        edge_norm<<<(E + B - 1) / B, B, 0, stream>>>(inc, segsum, out, E);
    } else if (ws_size >= needAtomic) {
        float* fromRec = (float*)ws;
        float* toRec   = fromRec + (size_t)NF * REC_STRIDE;
        float* segsum  = toRec + (size_t)NT * REC_STRIDE;
        hipMemsetAsync(segsum, 0, (size_t)NF * sizeof(float), stream);
        pre_node<<<(NF + B - 1) / B, B, 0, stream>>>(from_vec, from_frame, from_pos, W_from, W_attn, 0,  fromRec, NF);
        pre_node<<<(NT + B - 1) / B, B, 0, stream>>>(to_vec, to_frame, to_pos, W_to, W_attn, 12, toRec, NT);
        edge_score_at<<<(E + B - 1) / B, B, 0, stream>>>(inc, fromRec, toRec, W_attn, out, segsum, E);
        edge_norm<<<(E + B - 1) / B, B, 0, stream>>>(inc, segsum, out, E);
    }
}

// Round 5
// 126.220 us; speedup vs baseline: 1.6080x; 1.6080x over previous
//
#include <hip/hip_runtime.h>

// Node record layout (stride 16 floats = 64B):
//   [0..8]   Frame[k][j] (row-major)
//   [9..11]  pF[j] = sum_k pos[k]*Frame[k][j]
//   [12..14] pos[0..2]
//   [15]     sA = sum_{h,j} silu(A[h][j]) * Wa[waOff + h*3 + j]
#define REC_STRIDE 16

#define SEG_PAD 16   // floats per (key,replica) slot = one 64B line
#define NREP 2       // replicas per key, selected by lane parity

__device__ __forceinline__ float silu_f(float x)
{
    return x * __builtin_amdgcn_rcpf(1.f + __expf(-x));
}

__global__ void pre_node(const float* __restrict__ vec, const float* __restrict__ frame,
                         const float* __restrict__ pos, const float* __restrict__ W,
                         const float* __restrict__ Wa, int waOff,
                         float* __restrict__ out, int n)
{
    int i = blockIdx.x * blockDim.x + threadIdx.x;
    if (i >= n) return;

    float w[16][3];
#pragma unroll
    for (int d = 0; d < 16; ++d) {
        w[d][0] = W[d * 3 + 0];
        w[d][1] = W[d * 3 + 1];
        w[d][2] = W[d * 3 + 2];
    }
    float vt[3][3] = {{0.f}};  // [k][h]
    const float* vp = vec + (size_t)i * 48;
#pragma unroll
    for (int d = 0; d < 16; ++d) {
        float r0 = vp[d * 3 + 0], r1 = vp[d * 3 + 1], r2 = vp[d * 3 + 2];
#pragma unroll
        for (int h = 0; h < 3; ++h) {
            vt[0][h] += r0 * w[d][h];
            vt[1][h] += r1 * w[d][h];
            vt[2][h] += r2 * w[d][h];
        }
    }
    float F[9];
#pragma unroll
    for (int j = 0; j < 9; ++j) F[j] = frame[(size_t)i * 9 + j];
    float p0 = pos[(size_t)i * 3 + 0];
    float p1 = pos[(size_t)i * 3 + 1];
    float p2 = pos[(size_t)i * 3 + 2];

    float sA = 0.f;
#pragma unroll
    for (int h = 0; h < 3; ++h)
#pragma unroll
        for (int j = 0; j < 3; ++j) {
            float a = vt[0][h] * F[0 + j] + vt[1][h] * F[3 + j] + vt[2][h] * F[6 + j];
            sA += silu_f(a) * Wa[waOff + h * 3 + j];
        }

    float o[16];
#pragma unroll
    for (int j = 0; j < 9; ++j) o[j] = F[j];
#pragma unroll
    for (int j = 0; j < 3; ++j) o[9 + j] = p0 * F[j] + p1 * F[3 + j] + p2 * F[6 + j];
    o[12] = p0; o[13] = p1; o[14] = p2;
    o[15] = sA;

    float4* op = (float4*)(out + (size_t)i * REC_STRIDE);
#pragma unroll
    for (int q = 0; q < 4; ++q) op[q] = ((const float4*)o)[q];
}

// edge score with line-padded, replicated atomic segsum
__global__ void edge_score_pad(const int* __restrict__ inc,
                               const float* __restrict__ fromRec, const float* __restrict__ toRec,
                               const float* __restrict__ Wa,
                               float* __restrict__ ex_out, float* __restrict__ segsumP, int E)
{
    int e = blockIdx.x * blockDim.x + threadIdx.x;
    if (e >= E) return;
    int fi = __builtin_nontemporal_load(inc + e);
    int ti = __builtin_nontemporal_load(inc + E + e);

    float fr[16], tr[16];
    const float4* fp4 = (const float4*)(fromRec + (size_t)fi * REC_STRIDE);
    const float4* tp4 = (const float4*)(toRec + (size_t)ti * REC_STRIDE);
#pragma unroll
    for (int q = 0; q < 4; ++q) ((float4*)fr)[q] = fp4[q];
#pragma unroll
    for (int q = 0; q < 4; ++q) ((float4*)tr)[q] = tp4[q];

    float wa9 = Wa[9], wa10 = Wa[10], wa11 = Wa[11];
    float wa21 = Wa[21], wa22 = Wa[22], wa23 = Wa[23];

    float raw = fr[15] + tr[15];
#pragma unroll
    for (int j = 0; j < 3; ++j) {
        float fd = tr[12] * fr[j] + tr[13] * fr[3 + j] + tr[14] * fr[6 + j] - fr[9 + j];
        float td = fr[12] * tr[j] + fr[13] * tr[3 + j] + fr[14] * tr[6 + j] - tr[9 + j];
        float waf = (j == 0) ? wa9 : (j == 1) ? wa10 : wa11;
        float wat = (j == 0) ? wa21 : (j == 1) ? wa22 : wa23;
        raw += silu_f(fd) * waf + silu_f(td) * wat;
    }

    float ex = __expf(raw);  // shift-invariant softmax, |raw| << 80
    __builtin_nontemporal_store(ex, ex_out + e);

    // one 64B line per (key, replica); replica by lane parity so adjacent
    // lanes never touch the same line
    size_t slot = ((size_t)fi * NREP + (threadIdx.x & (NREP - 1))) * SEG_PAD;
    atomicAdd(&segsumP[slot], ex);
}

__global__ void seg_reduce(const float* __restrict__ segsumP, float* __restrict__ segsum, int NF)
{
    int k = blockIdx.x * blockDim.x + threadIdx.x;
    if (k >= NF) return;
    float s = 0.f;
#pragma unroll
    for (int r = 0; r < NREP; ++r) s += segsumP[((size_t)k * NREP + r) * SEG_PAD];
    segsum[k] = s;
}

__global__ void edge_norm(const int* __restrict__ inc, const float* __restrict__ segsum,
                          float* __restrict__ out, int E)
{
    int e = blockIdx.x * blockDim.x + threadIdx.x;
    if (e >= E) return;
    int fi = __builtin_nontemporal_load(inc + e);
    float ex = out[e];
    __builtin_nontemporal_store(ex * __builtin_amdgcn_rcpf(segsum[fi]), out + e);
}

// -------- fallback: unpadded atomic edge_score (validated round 2) ----------
__global__ void edge_score_at(const int* __restrict__ inc,
                              const float* __restrict__ fromRec, const float* __restrict__ toRec,
                              const float* __restrict__ Wa,
                              float* __restrict__ ex_out, float* __restrict__ segsum, int E)
{
    int e = blockIdx.x * blockDim.x + threadIdx.x;
    if (e >= E) return;
    int fi = inc[e];
    int ti = inc[E + e];
    float fr[16], tr[16];
    const float4* fp4 = (const float4*)(fromRec + (size_t)fi * REC_STRIDE);
    const float4* tp4 = (const float4*)(toRec + (size_t)ti * REC_STRIDE);
#pragma unroll
    for (int q = 0; q < 4; ++q) ((float4*)fr)[q] = fp4[q];
#pragma unroll
    for (int q = 0; q < 4; ++q) ((float4*)tr)[q] = tp4[q];
    float raw = fr[15] + tr[15];
#pragma unroll
    for (int j = 0; j < 3; ++j) {
        float fd = tr[12] * fr[j] + tr[13] * fr[3 + j] + tr[14] * fr[6 + j] - fr[9 + j];
        float td = fr[12] * tr[j] + fr[13] * tr[3 + j] + fr[14] * tr[6 + j] - tr[9 + j];
        raw += silu_f(fd) * Wa[9 + j] + silu_f(td) * Wa[21 + j];
    }
    float ex = __expf(raw);
    ex_out[e] = ex;
    atomicAdd(&segsum[fi], ex);
}

extern "C" void kernel_launch(void* const* d_in, const int* in_sizes, int n_in,
                              void* d_out, int out_size, void* d_ws, size_t ws_size,
                              hipStream_t stream)
{
    const float* from_vec   = (const float*)d_in[0];
    const float* to_vec     = (const float*)d_in[1];
    const float* from_frame = (const float*)d_in[2];
    const float* to_frame   = (const float*)d_in[3];
    const float* from_pos   = (const float*)d_in[4];
    const float* to_pos     = (const float*)d_in[5];
    const float* W_from     = (const float*)d_in[6];
    const float* W_to       = (const float*)d_in[7];
    const float* W_attn     = (const float*)d_in[8];
    const int*   inc        = (const int*)d_in[9];

    const int NF = in_sizes[0] / 48;   // 50000
    const int NT = in_sizes[1] / 48;   // 100000
    const int E  = in_sizes[9] / 2;    // 1600000

    float* out = (float*)d_out;
    unsigned char* ws = (unsigned char*)d_ws;

    const size_t recsz   = ((size_t)NF + NT) * REC_STRIDE * 4;         // 9.6MB
    const size_t padsz   = (size_t)NF * NREP * SEG_PAD * 4;            // 6.4MB
    const size_t needPad = recsz + padsz + (size_t)NF * 4;             // ~16.2MB
    const size_t needAt  = recsz + (size_t)NF * 4;                     // ~9.8MB

    const int B = 256;
    if (ws_size >= needPad) {
        float* fromRec = (float*)ws;
        float* toRec   = fromRec + (size_t)NF * REC_STRIDE;
        float* segsumP = toRec + (size_t)NT * REC_STRIDE;
        float* segsum  = segsumP + (size_t)NF * NREP * SEG_PAD;
        hipMemsetAsync(segsumP, 0, padsz, stream);
        pre_node<<<(NF + B - 1) / B, B, 0, stream>>>(from_vec, from_frame, from_pos, W_from, W_attn, 0,  fromRec, NF);
        pre_node<<<(NT + B - 1) / B, B, 0, stream>>>(to_vec, to_frame, to_pos, W_to, W_attn, 12, toRec, NT);
        edge_score_pad<<<(E + B - 1) / B, B, 0, stream>>>(inc, fromRec, toRec, W_attn, out, segsumP, E);
        seg_reduce<<<(NF + B - 1) / B, B, 0, stream>>>(segsumP, segsum, NF);
        edge_norm<<<(E + B - 1) / B, B, 0, stream>>>(inc, segsum, out, E);
    } else if (ws_size >= needAt) {
        float* fromRec = (float*)ws;
        float* toRec   = fromRec + (size_t)NF * REC_STRIDE;
        float* segsum  = toRec + (size_t)NT * REC_STRIDE;
        hipMemsetAsync(segsum, 0, (size_t)NF * sizeof(float), stream);
        pre_node<<<(NF + B - 1) / B, B, 0, stream>>>(from_vec, from_frame, from_pos, W_from, W_attn, 0,  fromRec, NF);
        pre_node<<<(NT + B - 1) / B, B, 0, stream>>>(to_vec, to_frame, to_pos, W_to, W_attn, 12, toRec, NT);
        edge_score_at<<<(E + B - 1) / B, B, 0, stream>>>(inc, fromRec, toRec, W_attn, out, segsum, E);
        edge_norm<<<(E + B - 1) / B, B, 0, stream>>>(inc, segsum, out, E);
    }
}